// Round 4
// baseline (298.676 us; speedup 1.0000x reference)
//
#include <hip/hip_runtime.h>
#include <hip/hip_bf16.h>
#include <math.h>

#define BB 8
#define NN 2048
#define DD 1024
#define LL 128
#define MM (BB*NN)   // 16384

typedef __attribute__((ext_vector_type(8))) short short8;
typedef __attribute__((ext_vector_type(8))) unsigned short ushort8;
typedef __attribute__((ext_vector_type(4))) float floatx4;

__device__ __forceinline__ void glds16(const void* g, void* l) {
    __builtin_amdgcn_global_load_lds(
        (const __attribute__((address_space(1))) unsigned int*)g,
        (__attribute__((address_space(3))) unsigned int*)l, 16, 0, 0);
}

// fp32 -> bf16 hi/lo split (RNE) of 8 consecutive elements at index i*8
__device__ __forceinline__ void split8(const float* __restrict__ x,
                                       unsigned short* __restrict__ hi,
                                       unsigned short* __restrict__ lo, int i) {
    const float4* xp = (const float4*)x + (size_t)i * 2;
    float4 v0 = xp[0], v1 = xp[1];
    float f[8] = {v0.x, v0.y, v0.z, v0.w, v1.x, v1.y, v1.z, v1.w};
    ushort8 h, l;
    #pragma unroll
    for (int e = 0; e < 8; ++e) {
        unsigned u = __float_as_uint(f[e]);
        unsigned r = u + 0x7FFFu + ((u >> 16) & 1u);
        unsigned short hb = (unsigned short)(r >> 16);
        float hf = __uint_as_float((unsigned)hb << 16);
        float res = f[e] - hf;
        unsigned u2 = __float_as_uint(res);
        unsigned r2 = u2 + 0x7FFFu + ((u2 >> 16) & 1u);
        h[e] = hb;
        l[e] = (unsigned short)(r2 >> 16);
    }
    *(ushort8*)(hi + (size_t)i * 8) = h;
    *(ushort8*)(lo + (size_t)i * 8) = l;
}

// ---------------- fused preprocessing: split(e_j), split(Wk)+zero(u), q = e_i @ Wq^T
__global__ __launch_bounds__(256) void prep_kernel(const float* __restrict__ e_j,
                                                   unsigned short* __restrict__ ehi,
                                                   unsigned short* __restrict__ elo,
                                                   const float* __restrict__ Wk,
                                                   unsigned short* __restrict__ wh,
                                                   unsigned short* __restrict__ wl,
                                                   const float* __restrict__ e_i,
                                                   const float* __restrict__ Wq,
                                                   float* __restrict__ q,
                                                   float* __restrict__ u) {
    int blk = blockIdx.x;
    int tid = threadIdx.x;
    if (blk < 8192) {
        split8(e_j, ehi, elo, blk * 256 + tid);
    } else if (blk < 8704) {
        split8(Wk, wh, wl, (blk - 8192) * 256 + tid);
        if (blk < 8224) u[(blk - 8192) * 256 + tid] = 0.f;   // zero u for later atomics
    } else {
        int wid  = ((blk - 8704) * 256 + tid) >> 6;   // 0..8191
        int lane = tid & 63;
        int r = wid >> 10;
        int d = wid & (DD - 1);
        const float* x = e_i + (size_t)r * DD;
        const float* w = Wq + (size_t)d * DD;
        float s = 0.f;
        #pragma unroll
        for (int e0 = 0; e0 < DD; e0 += 256) {
            float4 xv = *(const float4*)&x[e0 + lane * 4];
            float4 wv = *(const float4*)&w[e0 + lane * 4];
            s += xv.x * wv.x + xv.y * wv.y + xv.z * wv.z + xv.w * wv.w;
        }
        #pragma unroll
        for (int off = 32; off; off >>= 1) s += __shfl_down(s, off, 64);
        if (lane == 0) q[wid] = s;
    }
}

// ---------------- heavy kernel: bf16x3 MFMA GEMM + fused tanh(q+k)*omega row-reduce
// LDS bank-conflict fix: 16B k-units XOR-swizzled by h(row) = (row&2)|((row>>2)&1),
// applied on the global-fetch side (global_load_lds lane->LDS mapping is fixed).
__global__ __launch_bounds__(256) void sigma_mfma(const unsigned short* __restrict__ ehi,
                                                  const unsigned short* __restrict__ elo,
                                                  const unsigned short* __restrict__ wh,
                                                  const unsigned short* __restrict__ wl,
                                                  const float* __restrict__ q,
                                                  const float* __restrict__ omega,
                                                  float* __restrict__ sig_part)   // [8][MM]
{
    __shared__ unsigned short lds[4][128][32];
    __shared__ float red[128][2];

    const int tid  = threadIdx.x;
    const int lane = tid & 63;
    const int w    = tid >> 6;
    const int wr   = w >> 1, wc = w & 1;
    const int c15  = lane & 15, quad = lane >> 4;

    const int row0 = blockIdx.x * 128;
    const int col0 = blockIdx.y * 128;
    const int b    = row0 / NN;

    const int r0 = tid >> 2;
    const int hw = ((r0 & 2) | ((r0 >> 2) & 1));
    const int kk = (((tid & 3) ^ hw)) * 8;          // swizzled global k-unit for this thread

    const unsigned short* ga0 = ehi + (size_t)(row0 + r0) * DD + kk;
    const unsigned short* ga1 = ga0 + (size_t)64 * DD;
    const unsigned short* gb0 = elo + (size_t)(row0 + r0) * DD + kk;
    const unsigned short* gb1 = gb0 + (size_t)64 * DD;
    const unsigned short* gc0 = wh  + (size_t)(col0 + r0) * DD + kk;
    const unsigned short* gc1 = gc0 + (size_t)64 * DD;
    const unsigned short* gd0 = wl  + (size_t)(col0 + r0) * DD + kk;
    const unsigned short* gd1 = gd0 + (size_t)64 * DD;

    char* lbase = (char*)&lds[0][0][0] + w * 1024;

    // reader swizzle: physical unit = logical_quad ^ h(row); row bits 1,2 come from c15
    const int hsw = ((c15 & 2) | ((c15 >> 2) & 1));
    const int koff = ((quad ^ hsw)) * 8;

    floatx4 acc[4][4];
    #pragma unroll
    for (int i = 0; i < 4; ++i)
        #pragma unroll
        for (int j = 0; j < 4; ++j)
            acc[i][j] = (floatx4){0.f, 0.f, 0.f, 0.f};

    for (int k0 = 0; k0 < DD; k0 += 32) {
        glds16(ga0 + k0, lbase + 0 * 4096);
        glds16(ga1 + k0, lbase + 1 * 4096);
        glds16(gb0 + k0, lbase + 2 * 4096);
        glds16(gb1 + k0, lbase + 3 * 4096);
        glds16(gc0 + k0, lbase + 4 * 4096);
        glds16(gc1 + k0, lbase + 5 * 4096);
        glds16(gd0 + k0, lbase + 6 * 4096);
        glds16(gd1 + k0, lbase + 7 * 4096);
        __syncthreads();

        short8 ah[4], al[4], bh[4], bl[4];
        #pragma unroll
        for (int i = 0; i < 4; ++i) {
            ah[i] = *(const short8*)&lds[0][wr * 64 + i * 16 + c15][koff];
            al[i] = *(const short8*)&lds[1][wr * 64 + i * 16 + c15][koff];
            bh[i] = *(const short8*)&lds[2][wc * 64 + i * 16 + c15][koff];
            bl[i] = *(const short8*)&lds[3][wc * 64 + i * 16 + c15][koff];
        }
        #pragma unroll
        for (int i = 0; i < 4; ++i)
            #pragma unroll
            for (int j = 0; j < 4; ++j) {
                acc[i][j] = __builtin_amdgcn_mfma_f32_16x16x32_bf16(ah[i], bh[j], acc[i][j], 0, 0, 0);
                acc[i][j] = __builtin_amdgcn_mfma_f32_16x16x32_bf16(al[i], bh[j], acc[i][j], 0, 0, 0);
                acc[i][j] = __builtin_amdgcn_mfma_f32_16x16x32_bf16(ah[i], bl[j], acc[i][j], 0, 0, 0);
            }
        __syncthreads();
    }

    float part[4][4];
    #pragma unroll
    for (int i = 0; i < 4; ++i)
        #pragma unroll
        for (int r = 0; r < 4; ++r) part[i][r] = 0.f;

    #pragma unroll
    for (int j = 0; j < 4; ++j) {
        int c = col0 + wc * 64 + j * 16 + c15;
        float qv = q[b * DD + c];
        float om = omega[c];
        #pragma unroll
        for (int i = 0; i < 4; ++i)
            #pragma unroll
            for (int r = 0; r < 4; ++r)
                part[i][r] += tanhf(acc[i][j][r] + qv) * om;
    }
    #pragma unroll
    for (int i = 0; i < 4; ++i)
        #pragma unroll
        for (int r = 0; r < 4; ++r) {
            float s = part[i][r];
            s += __shfl_xor(s, 1, 64);
            s += __shfl_xor(s, 2, 64);
            s += __shfl_xor(s, 4, 64);
            s += __shfl_xor(s, 8, 64);
            if (c15 == 0) red[wr * 64 + i * 16 + quad * 4 + r][wc] = s;
        }
    __syncthreads();
    if (tid < 128)
        sig_part[blockIdx.y * MM + row0 + tid] = red[tid][0] + red[tid][1];
}

// ---------------- fused softmax-stats + u accumulation (512 blocks; 32 n-rows each)
// Each block recomputes (m, denom) for its b from sigp — redundant but L2-hot & cheap.
__global__ __launch_bounds__(256) void softu_kernel(const float* __restrict__ sigp,
                                                    const float* __restrict__ imp,
                                                    const float* __restrict__ ej,
                                                    float* __restrict__ u) {
    int b = blockIdx.x >> 6, nc = blockIdx.x & 63;
    int tid = threadIdx.x;
    __shared__ float red[256];
    __shared__ float aloc[32];

    float sv[8];
    float m = -1e30f;
    #pragma unroll
    for (int p = 0; p < 8; ++p) {
        int n = p * 256 + tid;
        float s = 0.f;
        #pragma unroll
        for (int db = 0; db < 8; ++db) s += sigp[db * MM + b * NN + n];
        sv[p] = s;
        m = fmaxf(m, s);
    }
    red[tid] = m; __syncthreads();
    for (int off = 128; off; off >>= 1) {
        if (tid < off) red[tid] = fmaxf(red[tid], red[tid + off]);
        __syncthreads();
    }
    m = red[0]; __syncthreads();
    float sum = 0.f;
    #pragma unroll
    for (int p = 0; p < 8; ++p) sum += expf(sv[p] - m);
    red[tid] = sum; __syncthreads();
    for (int off = 128; off; off >>= 1) {
        if (tid < off) red[tid] += red[tid + off];
        __syncthreads();
    }
    float inv = 1.f / (red[0] + 1e-9f * expf(-m));

    if (tid < 32) {
        int n = nc * 32 + tid;
        float s = 0.f;
        #pragma unroll
        for (int db = 0; db < 8; ++db) s += sigp[db * MM + b * NN + n];
        aloc[tid] = imp[b * NN + n] * expf(s - m) * inv;
    }
    __syncthreads();

    float4 acc = {0.f, 0.f, 0.f, 0.f};
    const float* base = ej + ((size_t)(b * NN + nc * 32)) * DD + tid * 4;
    #pragma unroll 4
    for (int n = 0; n < 32; ++n) {
        float a = aloc[n];
        float4 v = *(const float4*)(base + (size_t)n * DD);
        acc.x += a * v.x; acc.y += a * v.y; acc.z += a * v.z; acc.w += a * v.w;
    }
    float* up = u + b * DD + tid * 4;
    atomicAdd(up + 0, acc.x); atomicAdd(up + 1, acc.y);
    atomicAdd(up + 2, acc.z); atomicAdd(up + 3, acc.w);
}

// ---------------- fused A = u @ Wv^T + all three outputs (64 blocks: b x 128-d chunk)
__global__ __launch_bounds__(256) void aout_kernel(const float* __restrict__ u,
                                                   const float* __restrict__ Wv,
                                                   const float* __restrict__ Rlk,
                                                   float* __restrict__ out) {
    int b  = blockIdx.x >> 3;
    int d0 = (blockIdx.x & 7) * 128;
    int tid = threadIdx.x, lane = tid & 63, w = tid >> 6;
    __shared__ float us[DD];
    __shared__ float As[128];

    #pragma unroll
    for (int e0 = 0; e0 < DD; e0 += 256) us[e0 + tid] = u[b * DD + e0 + tid];
    __syncthreads();

    for (int j = 0; j < 32; ++j) {
        int d = d0 + w * 32 + j;
        const float* wr = Wv + (size_t)d * DD;
        float s = 0.f;
        #pragma unroll
        for (int e0 = 0; e0 < DD; e0 += 256) {
            float4 wv = *(const float4*)&wr[e0 + lane * 4];
            float4 uv = *(const float4*)&us[e0 + lane * 4];
            s += wv.x * uv.x + wv.y * uv.y + wv.z * uv.z + wv.w * uv.w;
        }
        #pragma unroll
        for (int off = 32; off; off >>= 1) s += __shfl_down(s, off, 64);
        if (lane == 0) As[w * 32 + j] = s;
    }
    __syncthreads();

    if (tid < 128) {
        out[b * DD + d0 + tid] = As[tid];                           // A
        out[BB * DD + BB * LL * DD + b * DD + d0 + tid] = As[tid];  // A_l
    }
    for (int idx = tid; idx < LL * 128; idx += 256) {
        int l = idx >> 7, dl = idx & 127;
        out[BB * DD + (size_t)b * LL * DD + l * DD + d0 + dl] = As[dl] * Rlk[l * DD + d0 + dl];
    }
}

extern "C" void kernel_launch(void* const* d_in, const int* in_sizes, int n_in,
                              void* d_out, int out_size, void* d_ws, size_t ws_size,
                              hipStream_t stream) {
    const float* e_i   = (const float*)d_in[0];
    const float* e_j   = (const float*)d_in[1];
    const float* imp   = (const float*)d_in[2];
    const float* Rlk   = (const float*)d_in[3];
    const float* Wq    = (const float*)d_in[4];
    const float* Wk    = (const float*)d_in[5];
    const float* Wv    = (const float*)d_in[6];
    const float* omega = (const float*)d_in[7];
    float* out = (float*)d_out;
    float* ws  = (float*)d_ws;

    float* q    = ws;               // 8192
    float* sigp = ws + 8192;        // 131072
    float* u    = ws + 155648;      // 8192
    unsigned short* ehi = (unsigned short*)(ws + 172032);
    unsigned short* elo = ehi + (size_t)MM * DD;
    unsigned short* wh  = elo + (size_t)MM * DD;
    unsigned short* wl  = wh + (size_t)DD * DD;

    // 1) split e_j, split Wk, zero u, q = e_i @ Wq^T
    prep_kernel<<<10752, 256, 0, stream>>>(e_j, ehi, elo, Wk, wh, wl, e_i, Wq, q, u);

    // 2) sigma partials: bf16x3 MFMA GEMM with fused tanh-omega reduction
    sigma_mfma<<<dim3(MM / 128, DD / 128), 256, 0, stream>>>(ehi, elo, wh, wl, q, omega, sigp);

    // 3) softmax stats + weighted e_j sum (u) in one kernel
    softu_kernel<<<512, 256, 0, stream>>>(sigp, imp, e_j, u);

    // 4) A = u @ Wv^T and all outputs
    aout_kernel<<<64, 256, 0, stream>>>(u, Wv, Rlk, out);
}

// Round 5
// 272.649 us; speedup vs baseline: 1.0955x; 1.0955x over previous
//
#include <hip/hip_runtime.h>
#include <hip/hip_bf16.h>
#include <math.h>

#define BB 8
#define NN 2048
#define DD 1024
#define LL 128
#define MM (BB*NN)   // 16384

typedef __attribute__((ext_vector_type(8))) short short8;
typedef __attribute__((ext_vector_type(8))) unsigned short ushort8;
typedef __attribute__((ext_vector_type(16))) float floatx16;

__device__ __forceinline__ void glds16(const void* g, void* l) {
    __builtin_amdgcn_global_load_lds(
        (const __attribute__((address_space(1))) unsigned int*)g,
        (__attribute__((address_space(3))) unsigned int*)l, 16, 0, 0);
}

// fp32 -> bf16 hi/lo split (RNE) of 8 consecutive elements at index i*8
__device__ __forceinline__ void split8(const float* __restrict__ x,
                                       unsigned short* __restrict__ hi,
                                       unsigned short* __restrict__ lo, int i) {
    const float4* xp = (const float4*)x + (size_t)i * 2;
    float4 v0 = xp[0], v1 = xp[1];
    float f[8] = {v0.x, v0.y, v0.z, v0.w, v1.x, v1.y, v1.z, v1.w};
    ushort8 h, l;
    #pragma unroll
    for (int e = 0; e < 8; ++e) {
        unsigned u = __float_as_uint(f[e]);
        unsigned r = u + 0x7FFFu + ((u >> 16) & 1u);
        unsigned short hb = (unsigned short)(r >> 16);
        float hf = __uint_as_float((unsigned)hb << 16);
        float res = f[e] - hf;
        unsigned u2 = __float_as_uint(res);
        unsigned r2 = u2 + 0x7FFFu + ((u2 >> 16) & 1u);
        h[e] = hb;
        l[e] = (unsigned short)(r2 >> 16);
    }
    *(ushort8*)(hi + (size_t)i * 8) = h;
    *(ushort8*)(lo + (size_t)i * 8) = l;
}

// ---------------- fused preprocessing: split(e_j), split(Wk)+zero(u), q = e_i @ Wq^T
__global__ __launch_bounds__(256) void prep_kernel(const float* __restrict__ e_j,
                                                   unsigned short* __restrict__ ehi,
                                                   unsigned short* __restrict__ elo,
                                                   const float* __restrict__ Wk,
                                                   unsigned short* __restrict__ wh,
                                                   unsigned short* __restrict__ wl,
                                                   const float* __restrict__ e_i,
                                                   const float* __restrict__ Wq,
                                                   float* __restrict__ q,
                                                   float* __restrict__ u) {
    int blk = blockIdx.x;
    int tid = threadIdx.x;
    if (blk < 8192) {
        split8(e_j, ehi, elo, blk * 256 + tid);
    } else if (blk < 8704) {
        split8(Wk, wh, wl, (blk - 8192) * 256 + tid);
        if (blk < 8224) u[(blk - 8192) * 256 + tid] = 0.f;
    } else {
        int wid  = ((blk - 8704) * 256 + tid) >> 6;   // 0..8191
        int lane = tid & 63;
        int r = wid >> 10;
        int d = wid & (DD - 1);
        const float* x = e_i + (size_t)r * DD;
        const float* w = Wq + (size_t)d * DD;
        float s = 0.f;
        #pragma unroll
        for (int e0 = 0; e0 < DD; e0 += 256) {
            float4 xv = *(const float4*)&x[e0 + lane * 4];
            float4 wv = *(const float4*)&w[e0 + lane * 4];
            s += xv.x * wv.x + xv.y * wv.y + xv.z * wv.z + xv.w * wv.w;
        }
        #pragma unroll
        for (int off = 32; off; off >>= 1) s += __shfl_down(s, off, 64);
        if (lane == 0) q[wid] = s;
    }
}

// ---------------- heavy kernel: bf16x3 MFMA GEMM (32x32x16) + fused tanh(q+k)*omega
// Block tile 256x128, BK=32; 4 waves in 2x2; wave tile 128x64 = 4x2 of 32x32 MFMA.
// 24 frag-reads feed 48 MFMAs per wave k-iter (4.0 MFMA/ds_read vs 3.0 before).
__global__ __launch_bounds__(256, 2) void sigma_mfma(const unsigned short* __restrict__ ehi,
                                                     const unsigned short* __restrict__ elo,
                                                     const unsigned short* __restrict__ wh,
                                                     const unsigned short* __restrict__ wl,
                                                     const float* __restrict__ q,
                                                     const float* __restrict__ omega,
                                                     float* __restrict__ sig_part)   // [8][MM]
{
    __shared__ unsigned short Ah[256][32];   // 16 KB
    __shared__ unsigned short Al[256][32];   // 16 KB
    __shared__ unsigned short Bh[128][32];   // 8 KB
    __shared__ unsigned short Bl[128][32];   // 8 KB
    __shared__ float red[256][2];

    const int tid  = threadIdx.x;
    const int lane = tid & 63;
    const int w    = tid >> 6;
    const int wr   = w >> 1, wc = w & 1;
    const int m32  = lane & 31, half = lane >> 5;

    const int row0 = blockIdx.x * 256;
    const int col0 = blockIdx.y * 128;
    const int b    = row0 / NN;

    // staging: thread tid loads 16B (8 shorts) from global row (i*64 + tid>>2), k-unit (tid&3)
    const int r0 = tid >> 2;
    const int ku = (tid & 3) * 8;

    const unsigned short* gAh = ehi + (size_t)(row0 + r0) * DD + ku;
    const unsigned short* gAl = elo + (size_t)(row0 + r0) * DD + ku;
    const unsigned short* gBh = wh  + (size_t)(col0 + r0) * DD + ku;
    const unsigned short* gBl = wl  + (size_t)(col0 + r0) * DD + ku;

    char* dAh = (char*)&Ah[0][0] + w * 1024;
    char* dAl = (char*)&Al[0][0] + w * 1024;
    char* dBh = (char*)&Bh[0][0] + w * 1024;
    char* dBl = (char*)&Bl[0][0] + w * 1024;

    floatx16 acc[4][2];
    #pragma unroll
    for (int t = 0; t < 4; ++t)
        #pragma unroll
        for (int c = 0; c < 2; ++c)
            #pragma unroll
            for (int r = 0; r < 16; ++r) acc[t][c][r] = 0.f;

    for (int k0 = 0; k0 < DD; k0 += 32) {
        #pragma unroll
        for (int i = 0; i < 4; ++i) {
            glds16(gAh + (size_t)i * 64 * DD + k0, dAh + i * 4096);
            glds16(gAl + (size_t)i * 64 * DD + k0, dAl + i * 4096);
        }
        #pragma unroll
        for (int i = 0; i < 2; ++i) {
            glds16(gBh + (size_t)i * 64 * DD + k0, dBh + i * 4096);
            glds16(gBl + (size_t)i * 64 * DD + k0, dBl + i * 4096);
        }
        __syncthreads();

        #pragma unroll
        for (int s = 0; s < 2; ++s) {
            const int koff = s * 16 + half * 8;
            short8 a_h[4], a_l[4], b_h[2], b_l[2];
            #pragma unroll
            for (int t = 0; t < 4; ++t) {
                a_h[t] = *(const short8*)&Ah[wr * 128 + t * 32 + m32][koff];
                a_l[t] = *(const short8*)&Al[wr * 128 + t * 32 + m32][koff];
            }
            #pragma unroll
            for (int c = 0; c < 2; ++c) {
                b_h[c] = *(const short8*)&Bh[wc * 64 + c * 32 + m32][koff];
                b_l[c] = *(const short8*)&Bl[wc * 64 + c * 32 + m32][koff];
            }
            #pragma unroll
            for (int t = 0; t < 4; ++t)
                #pragma unroll
                for (int c = 0; c < 2; ++c) {
                    acc[t][c] = __builtin_amdgcn_mfma_f32_32x32x16_bf16(a_h[t], b_h[c], acc[t][c], 0, 0, 0);
                    acc[t][c] = __builtin_amdgcn_mfma_f32_32x32x16_bf16(a_l[t], b_h[c], acc[t][c], 0, 0, 0);
                    acc[t][c] = __builtin_amdgcn_mfma_f32_32x32x16_bf16(a_h[t], b_l[c], acc[t][c], 0, 0, 0);
                }
        }
        __syncthreads();
    }

    // epilogue: per-row partial sum of tanh(k+q)*omega over this block's 128 cols.
    // C/D layout (m74/m101): col = lane&31, row = (r&3) + 8*(r>>2) + 4*half.
    float part[4][16];
    #pragma unroll
    for (int t = 0; t < 4; ++t)
        #pragma unroll
        for (int r = 0; r < 16; ++r) part[t][r] = 0.f;

    #pragma unroll
    for (int c = 0; c < 2; ++c) {
        int col = col0 + wc * 64 + c * 32 + m32;
        float qv = q[b * DD + col];
        float om = omega[col];
        #pragma unroll
        for (int t = 0; t < 4; ++t)
            #pragma unroll
            for (int r = 0; r < 16; ++r)
                part[t][r] += tanhf(acc[t][c][r] + qv) * om;
    }
    #pragma unroll
    for (int t = 0; t < 4; ++t)
        #pragma unroll
        for (int r = 0; r < 16; ++r) {
            float s = part[t][r];
            s += __shfl_xor(s, 1, 64);
            s += __shfl_xor(s, 2, 64);
            s += __shfl_xor(s, 4, 64);
            s += __shfl_xor(s, 8, 64);
            s += __shfl_xor(s, 16, 64);
            if (m32 == 0)
                red[wr * 128 + t * 32 + (r & 3) + 8 * (r >> 2) + 4 * half][wc] = s;
        }
    __syncthreads();
    sig_part[blockIdx.y * MM + row0 + tid] = red[tid][0] + red[tid][1];
}

// ---------------- per-b softmax-style weights (64 blocks: 8 per b, full stats each)
__global__ __launch_bounds__(256) void softmax_k(const float* __restrict__ sig_part,
                                                 const float* __restrict__ imp,
                                                 float* __restrict__ a_ij) {
    int b = blockIdx.x >> 3, slice = blockIdx.x & 7;
    int tid = threadIdx.x;
    __shared__ float red[256];
    float sv[8];
    float m = -1e30f;
    #pragma unroll
    for (int p = 0; p < 8; ++p) {
        int n = p * 256 + tid;
        float s = 0.f;
        #pragma unroll
        for (int db = 0; db < 8; ++db) s += sig_part[db * MM + b * NN + n];
        sv[p] = s;
        m = fmaxf(m, s);
    }
    red[tid] = m; __syncthreads();
    for (int off = 128; off; off >>= 1) {
        if (tid < off) red[tid] = fmaxf(red[tid], red[tid + off]);
        __syncthreads();
    }
    m = red[0]; __syncthreads();
    float sum = 0.f;
    #pragma unroll
    for (int p = 0; p < 8; ++p) sum += expf(sv[p] - m);
    red[tid] = sum; __syncthreads();
    for (int off = 128; off; off >>= 1) {
        if (tid < off) red[tid] += red[tid + off];
        __syncthreads();
    }
    float inv = 1.f / (red[0] + 1e-9f * expf(-m));
    int n = slice * 256 + tid;
    a_ij[b * NN + n] = imp[b * NN + n] * expf(sv[slice] - m) * inv;
}

// ---------------- u[b,e] = sum_n a_ij[b,n] * e_j[b,n,e]  (512 blocks, 32 rows each)
__global__ __launch_bounds__(256) void u_kernel(const float* __restrict__ a_ij,
                                                const float* __restrict__ ej,
                                                float* __restrict__ u) {
    int b = blockIdx.x >> 6, nc = blockIdx.x & 63;
    int t = threadIdx.x;
    float4 acc = {0.f, 0.f, 0.f, 0.f};
    const float* base = ej + ((size_t)(b * NN + nc * 32)) * DD + t * 4;
    const float* ap = a_ij + b * NN + nc * 32;
    #pragma unroll 4
    for (int n = 0; n < 32; ++n) {
        float a = ap[n];
        float4 v = *(const float4*)(base + (size_t)n * DD);
        acc.x += a * v.x; acc.y += a * v.y; acc.z += a * v.z; acc.w += a * v.w;
    }
    float* up = u + b * DD + t * 4;
    atomicAdd(up + 0, acc.x); atomicAdd(up + 1, acc.y);
    atomicAdd(up + 2, acc.z); atomicAdd(up + 3, acc.w);
}

// ---------------- A = u @ Wv^T
__global__ __launch_bounds__(256) void rowdot_A(const float* __restrict__ X,
                                                const float* __restrict__ W,
                                                float* __restrict__ out) {
    int wid  = (blockIdx.x * blockDim.x + threadIdx.x) >> 6;
    int lane = threadIdx.x & 63;
    int r = wid >> 10;
    int d = wid & (DD - 1);
    const float* x = X + (size_t)r * DD;
    const float* w = W + (size_t)d * DD;
    float s = 0.f;
    #pragma unroll
    for (int e0 = 0; e0 < DD; e0 += 256) {
        float4 xv = *(const float4*)&x[e0 + lane * 4];
        float4 wv = *(const float4*)&w[e0 + lane * 4];
        s += xv.x * wv.x + xv.y * wv.y + xv.z * wv.z + xv.w * wv.w;
    }
    #pragma unroll
    for (int off = 32; off; off >>= 1) s += __shfl_down(s, off, 64);
    if (lane == 0) out[wid] = s;
}

// ---------------- outputs: A, A_lk = A*R, A_l = A
__global__ __launch_bounds__(256) void out_kernel(const float* __restrict__ A,
                                                  const float* __restrict__ Rlk,
                                                  float* __restrict__ out) {
    int i = blockIdx.x * 256 + threadIdx.x;
    int d = i & (DD - 1);
    int l = (i >> 10) & (LL - 1);
    int b = i >> 17;
    out[BB * DD + i] = A[b * DD + d] * Rlk[l * DD + d];
    if (i < BB * DD) {
        out[i] = A[i];
        out[BB * DD + BB * LL * DD + i] = A[i];
    }
}

extern "C" void kernel_launch(void* const* d_in, const int* in_sizes, int n_in,
                              void* d_out, int out_size, void* d_ws, size_t ws_size,
                              hipStream_t stream) {
    const float* e_i   = (const float*)d_in[0];
    const float* e_j   = (const float*)d_in[1];
    const float* imp   = (const float*)d_in[2];
    const float* Rlk   = (const float*)d_in[3];
    const float* Wq    = (const float*)d_in[4];
    const float* Wk    = (const float*)d_in[5];
    const float* Wv    = (const float*)d_in[6];
    const float* omega = (const float*)d_in[7];
    float* out = (float*)d_out;
    float* ws  = (float*)d_ws;

    float* q    = ws;               // 8192
    float* sigp = ws + 8192;        // 131072
    float* a_ij = ws + 139264;      // 16384
    float* u    = ws + 155648;      // 8192
    unsigned short* ehi = (unsigned short*)(ws + 172032);
    unsigned short* elo = ehi + (size_t)MM * DD;
    unsigned short* wh  = elo + (size_t)MM * DD;
    unsigned short* wl  = wh + (size_t)DD * DD;

    // 1) split e_j, split Wk, zero u, q = e_i @ Wq^T
    prep_kernel<<<10752, 256, 0, stream>>>(e_j, ehi, elo, Wk, wh, wl, e_i, Wq, q, u);

    // 2) sigma partials: bf16x3 MFMA GEMM (32x32x16, 256x128 tiles)
    sigma_mfma<<<dim3(MM / 256, DD / 128), 256, 0, stream>>>(ehi, elo, wh, wl, q, omega, sigp);

    // 3) a_ij
    softmax_k<<<64, 256, 0, stream>>>(sigp, imp, a_ij);

    // 4) u = a_ij-weighted sum of e_j rows
    u_kernel<<<512, 256, 0, stream>>>(a_ij, e_j, u);

    // 5) A = u @ Wv^T
    rowdot_A<<<2048, 256, 0, stream>>>(u, Wv, a_ij);   // reuse a_ij head as Abuf (8192 floats)

    // 6) outputs
    out_kernel<<<(BB * LL * DD) / 256, 256, 0, stream>>>(a_ij, Rlk, out);
}

// Round 6
// 269.967 us; speedup vs baseline: 1.1063x; 1.0099x over previous
//
#include <hip/hip_runtime.h>
#include <hip/hip_bf16.h>
#include <math.h>

#define BB 8
#define NN 2048
#define DD 1024
#define LL 128
#define MM (BB*NN)   // 16384

typedef __attribute__((ext_vector_type(8))) short short8;
typedef __attribute__((ext_vector_type(8))) unsigned short ushort8;
typedef __attribute__((ext_vector_type(4))) float floatx4;

__device__ __forceinline__ void glds16(const void* g, void* l) {
    __builtin_amdgcn_global_load_lds(
        (const __attribute__((address_space(1))) unsigned int*)g,
        (__attribute__((address_space(3))) unsigned int*)l, 16, 0, 0);
}

// fp32 -> bf16 hi/lo split (RNE) of 8 consecutive elements at index i*8
__device__ __forceinline__ void split8(const float* __restrict__ x,
                                       unsigned short* __restrict__ hi,
                                       unsigned short* __restrict__ lo, int i) {
    const float4* xp = (const float4*)x + (size_t)i * 2;
    float4 v0 = xp[0], v1 = xp[1];
    float f[8] = {v0.x, v0.y, v0.z, v0.w, v1.x, v1.y, v1.z, v1.w};
    ushort8 h, l;
    #pragma unroll
    for (int e = 0; e < 8; ++e) {
        unsigned u = __float_as_uint(f[e]);
        unsigned r = u + 0x7FFFu + ((u >> 16) & 1u);
        unsigned short hb = (unsigned short)(r >> 16);
        float hf = __uint_as_float((unsigned)hb << 16);
        float res = f[e] - hf;
        unsigned u2 = __float_as_uint(res);
        unsigned r2 = u2 + 0x7FFFu + ((u2 >> 16) & 1u);
        h[e] = hb;
        l[e] = (unsigned short)(r2 >> 16);
    }
    *(ushort8*)(hi + (size_t)i * 8) = h;
    *(ushort8*)(lo + (size_t)i * 8) = l;
}

// ---------------- fused preprocessing: split(e_j), split(Wk), q = e_i @ Wq^T
__global__ __launch_bounds__(256) void prep_kernel(const float* __restrict__ e_j,
                                                   unsigned short* __restrict__ ehi,
                                                   unsigned short* __restrict__ elo,
                                                   const float* __restrict__ Wk,
                                                   unsigned short* __restrict__ wh,
                                                   unsigned short* __restrict__ wl,
                                                   const float* __restrict__ e_i,
                                                   const float* __restrict__ Wq,
                                                   float* __restrict__ q) {
    int blk = blockIdx.x;
    int tid = threadIdx.x;
    if (blk < 8192) {
        split8(e_j, ehi, elo, blk * 256 + tid);
    } else if (blk < 8704) {
        split8(Wk, wh, wl, (blk - 8192) * 256 + tid);
    } else {
        int wid  = ((blk - 8704) * 256 + tid) >> 6;   // 0..8191
        int lane = tid & 63;
        int r = wid >> 10;
        int d = wid & (DD - 1);
        const float* x = e_i + (size_t)r * DD;
        const float* w = Wq + (size_t)d * DD;
        float s = 0.f;
        #pragma unroll
        for (int e0 = 0; e0 < DD; e0 += 256) {
            float4 xv = *(const float4*)&x[e0 + lane * 4];
            float4 wv = *(const float4*)&w[e0 + lane * 4];
            s += xv.x * wv.x + xv.y * wv.y + xv.z * wv.z + xv.w * wv.w;
        }
        #pragma unroll
        for (int off = 32; off; off >>= 1) s += __shfl_down(s, off, 64);
        if (lane == 0) q[wid] = s;
    }
}

// ---------------- heavy kernel: bf16x3 MFMA GEMM + fused tanh(q+k)*omega row-reduce
// (R2 version verbatim — measured 124-126 us; m97-plateau structure, leave alone.)
__global__ __launch_bounds__(256) void sigma_mfma(const unsigned short* __restrict__ ehi,
                                                  const unsigned short* __restrict__ elo,
                                                  const unsigned short* __restrict__ wh,
                                                  const unsigned short* __restrict__ wl,
                                                  const float* __restrict__ q,
                                                  const float* __restrict__ omega,
                                                  float* __restrict__ sig_part)   // [8][MM]
{
    __shared__ unsigned short lds[4][128][32];
    __shared__ float red[128][2];

    const int tid  = threadIdx.x;
    const int lane = tid & 63;
    const int w    = tid >> 6;
    const int wr   = w >> 1, wc = w & 1;
    const int c15  = lane & 15, quad = lane >> 4;

    const int row0 = blockIdx.x * 128;
    const int col0 = blockIdx.y * 128;
    const int b    = row0 / NN;

    const int r0 = tid >> 2;
    const int kk = (tid & 3) * 8;

    const unsigned short* ga0 = ehi + (size_t)(row0 + r0) * DD + kk;
    const unsigned short* ga1 = ga0 + (size_t)64 * DD;
    const unsigned short* gb0 = elo + (size_t)(row0 + r0) * DD + kk;
    const unsigned short* gb1 = gb0 + (size_t)64 * DD;
    const unsigned short* gc0 = wh  + (size_t)(col0 + r0) * DD + kk;
    const unsigned short* gc1 = gc0 + (size_t)64 * DD;
    const unsigned short* gd0 = wl  + (size_t)(col0 + r0) * DD + kk;
    const unsigned short* gd1 = gd0 + (size_t)64 * DD;

    char* lbase = (char*)&lds[0][0][0] + w * 1024;

    floatx4 acc[4][4];
    #pragma unroll
    for (int i = 0; i < 4; ++i)
        #pragma unroll
        for (int j = 0; j < 4; ++j)
            acc[i][j] = (floatx4){0.f, 0.f, 0.f, 0.f};

    for (int k0 = 0; k0 < DD; k0 += 32) {
        glds16(ga0 + k0, lbase + 0 * 4096);
        glds16(ga1 + k0, lbase + 1 * 4096);
        glds16(gb0 + k0, lbase + 2 * 4096);
        glds16(gb1 + k0, lbase + 3 * 4096);
        glds16(gc0 + k0, lbase + 4 * 4096);
        glds16(gc1 + k0, lbase + 5 * 4096);
        glds16(gd0 + k0, lbase + 6 * 4096);
        glds16(gd1 + k0, lbase + 7 * 4096);
        __syncthreads();

        short8 ah[4], al[4], bh[4], bl[4];
        #pragma unroll
        for (int i = 0; i < 4; ++i) {
            ah[i] = *(const short8*)&lds[0][wr * 64 + i * 16 + c15][quad * 8];
            al[i] = *(const short8*)&lds[1][wr * 64 + i * 16 + c15][quad * 8];
            bh[i] = *(const short8*)&lds[2][wc * 64 + i * 16 + c15][quad * 8];
            bl[i] = *(const short8*)&lds[3][wc * 64 + i * 16 + c15][quad * 8];
        }
        #pragma unroll
        for (int i = 0; i < 4; ++i)
            #pragma unroll
            for (int j = 0; j < 4; ++j) {
                acc[i][j] = __builtin_amdgcn_mfma_f32_16x16x32_bf16(ah[i], bh[j], acc[i][j], 0, 0, 0);
                acc[i][j] = __builtin_amdgcn_mfma_f32_16x16x32_bf16(al[i], bh[j], acc[i][j], 0, 0, 0);
                acc[i][j] = __builtin_amdgcn_mfma_f32_16x16x32_bf16(ah[i], bl[j], acc[i][j], 0, 0, 0);
            }
        __syncthreads();
    }

    float part[4][4];
    #pragma unroll
    for (int i = 0; i < 4; ++i)
        #pragma unroll
        for (int r = 0; r < 4; ++r) part[i][r] = 0.f;

    #pragma unroll
    for (int j = 0; j < 4; ++j) {
        int c = col0 + wc * 64 + j * 16 + c15;
        float qv = q[b * DD + c];
        float om = omega[c];
        #pragma unroll
        for (int i = 0; i < 4; ++i)
            #pragma unroll
            for (int r = 0; r < 4; ++r)
                part[i][r] += tanhf(acc[i][j][r] + qv) * om;
    }
    #pragma unroll
    for (int i = 0; i < 4; ++i)
        #pragma unroll
        for (int r = 0; r < 4; ++r) {
            float s = part[i][r];
            s += __shfl_xor(s, 1, 64);
            s += __shfl_xor(s, 2, 64);
            s += __shfl_xor(s, 4, 64);
            s += __shfl_xor(s, 8, 64);
            if (c15 == 0) red[wr * 64 + i * 16 + quad * 4 + r][wc] = s;
        }
    __syncthreads();
    if (tid < 128)
        sig_part[blockIdx.y * MM + row0 + tid] = red[tid][0] + red[tid][1];
}

// ---------------- per-b softmax-style weights (64 blocks: 8 per b, full stats each)
__global__ __launch_bounds__(256) void softmax_k(const float* __restrict__ sig_part,
                                                 const float* __restrict__ imp,
                                                 float* __restrict__ a_ij) {
    int b = blockIdx.x >> 3, slice = blockIdx.x & 7;
    int tid = threadIdx.x;
    __shared__ float red[256];
    float sv[8];
    float m = -1e30f;
    #pragma unroll
    for (int p = 0; p < 8; ++p) {
        int n = p * 256 + tid;
        float s = 0.f;
        #pragma unroll
        for (int db = 0; db < 8; ++db) s += sig_part[db * MM + b * NN + n];
        sv[p] = s;
        m = fmaxf(m, s);
    }
    red[tid] = m; __syncthreads();
    for (int off = 128; off; off >>= 1) {
        if (tid < off) red[tid] = fmaxf(red[tid], red[tid + off]);
        __syncthreads();
    }
    m = red[0]; __syncthreads();
    float sum = 0.f;
    #pragma unroll
    for (int p = 0; p < 8; ++p) sum += expf(sv[p] - m);
    red[tid] = sum; __syncthreads();
    for (int off = 128; off; off >>= 1) {
        if (tid < off) red[tid] += red[tid + off];
        __syncthreads();
    }
    float inv = 1.f / (red[0] + 1e-9f * expf(-m));
    int n = slice * 256 + tid;
    a_ij[b * NN + n] = imp[b * NN + n] * expf(sv[slice] - m) * inv;
}

// ---------------- u partials: NO atomics. 1024 blocks = 8 b x 128 chunks of 16 rows.
// u_part[nc][b][e] — each block writes a disjoint 4 KB slice.
__global__ __launch_bounds__(256) void u_kernel(const float* __restrict__ a_ij,
                                                const float* __restrict__ ej,
                                                float* __restrict__ u_part) {
    int b = blockIdx.x >> 7, nc = blockIdx.x & 127;
    int t = threadIdx.x;
    float4 acc = {0.f, 0.f, 0.f, 0.f};
    const float* base = ej + ((size_t)(b * NN + nc * 16)) * DD + t * 4;
    const float* ap = a_ij + b * NN + nc * 16;
    #pragma unroll
    for (int n = 0; n < 16; ++n) {
        float a = ap[n];
        float4 v = *(const float4*)(base + (size_t)n * DD);
        acc.x += a * v.x; acc.y += a * v.y; acc.z += a * v.z; acc.w += a * v.w;
    }
    *(float4*)(u_part + ((size_t)nc * BB + b) * DD + t * 4) = acc;
}

// ---------------- u[b,e] = sum over 128 partials
__global__ __launch_bounds__(256) void ureduce(const float* __restrict__ u_part,
                                               float* __restrict__ u) {
    int i = blockIdx.x * 256 + threadIdx.x;   // < 8192
    float s = 0.f;
    #pragma unroll 8
    for (int nc = 0; nc < 128; ++nc) s += u_part[(size_t)nc * BB * DD + i];
    u[i] = s;
}

// ---------------- A = u @ Wv^T
__global__ __launch_bounds__(256) void rowdot_A(const float* __restrict__ X,
                                                const float* __restrict__ W,
                                                float* __restrict__ out) {
    int wid  = (blockIdx.x * blockDim.x + threadIdx.x) >> 6;
    int lane = threadIdx.x & 63;
    int r = wid >> 10;
    int d = wid & (DD - 1);
    const float* x = X + (size_t)r * DD;
    const float* w = W + (size_t)d * DD;
    float s = 0.f;
    #pragma unroll
    for (int e0 = 0; e0 < DD; e0 += 256) {
        float4 xv = *(const float4*)&x[e0 + lane * 4];
        float4 wv = *(const float4*)&w[e0 + lane * 4];
        s += xv.x * wv.x + xv.y * wv.y + xv.z * wv.z + xv.w * wv.w;
    }
    #pragma unroll
    for (int off = 32; off; off >>= 1) s += __shfl_down(s, off, 64);
    if (lane == 0) out[wid] = s;
}

// ---------------- outputs: A, A_lk = A*R, A_l = A
__global__ __launch_bounds__(256) void out_kernel(const float* __restrict__ A,
                                                  const float* __restrict__ Rlk,
                                                  float* __restrict__ out) {
    int i = blockIdx.x * 256 + threadIdx.x;
    int d = i & (DD - 1);
    int l = (i >> 10) & (LL - 1);
    int b = i >> 17;
    out[BB * DD + i] = A[b * DD + d] * Rlk[l * DD + d];
    if (i < BB * DD) {
        out[i] = A[i];
        out[BB * DD + BB * LL * DD + i] = A[i];
    }
}

extern "C" void kernel_launch(void* const* d_in, const int* in_sizes, int n_in,
                              void* d_out, int out_size, void* d_ws, size_t ws_size,
                              hipStream_t stream) {
    const float* e_i   = (const float*)d_in[0];
    const float* e_j   = (const float*)d_in[1];
    const float* imp   = (const float*)d_in[2];
    const float* Rlk   = (const float*)d_in[3];
    const float* Wq    = (const float*)d_in[4];
    const float* Wk    = (const float*)d_in[5];
    const float* Wv    = (const float*)d_in[6];
    const float* omega = (const float*)d_in[7];
    float* out = (float*)d_out;
    float* ws  = (float*)d_ws;

    float* q    = ws;               // 8192
    float* sigp = ws + 8192;        // 131072
    float* a_ij = ws + 139264;      // 16384
    float* u    = ws + 155648;      // 8192
    unsigned short* ehi = (unsigned short*)(ws + 172032);
    unsigned short* elo = ehi + (size_t)MM * DD;
    unsigned short* wh  = elo + (size_t)MM * DD;
    unsigned short* wl  = wh + (size_t)DD * DD;
    // u_part aliases wh/wl (dead after sigma): 128*8*1024 floats = 4 MB exactly
    float* u_part = (float*)wh;

    // 1) split e_j, split Wk, q = e_i @ Wq^T
    prep_kernel<<<10752, 256, 0, stream>>>(e_j, ehi, elo, Wk, wh, wl, e_i, Wq, q);

    // 2) sigma partials: bf16x3 MFMA GEMM (16x16x32, 128x128 tiles)
    sigma_mfma<<<dim3(MM / 128, DD / 128), 256, 0, stream>>>(ehi, elo, wh, wl, q, omega, sigp);

    // 3) a_ij
    softmax_k<<<64, 256, 0, stream>>>(sigp, imp, a_ij);

    // 4) u partials (no atomics), then reduce
    u_kernel<<<1024, 256, 0, stream>>>(a_ij, e_j, u_part);
    ureduce<<<32, 256, 0, stream>>>(u_part, u);

    // 5) A = u @ Wv^T  (reuse a_ij head as Abuf)
    rowdot_A<<<2048, 256, 0, stream>>>(u, Wv, a_ij);

    // 6) outputs
    out_kernel<<<(BB * LL * DD) / 256, 256, 0, stream>>>(a_ij, Rlk, out);
}